// Round 1
// baseline (234.212 us; speedup 1.0000x reference)
//
#include <hip/hip_runtime.h>

// Problem: B=4, C=64, H=64, W=64. Tokens N = C*H = 4096, feature dim D = W = 64.
// q = conv1x1(v1,wq,bq); k,v = conv1x1(v2,...); scores = q@k^T (no 1/sqrt(d));
// softmax; out = attn@v. Output fp32, same flat layout as input (B,C,H,W).
//
// Key identity: qf[b, n=o*64+h, w] flat == conv output y[b,o,hw=h*64+w] flat.
// So the conv kernel writes the "token-major" layout for free.

#define Bn 4
#define Cc 64
#define HW 4096
#define Nn 4096
#define Dd 64
#define TS (Bn * Nn * Dd)   // elems per (B,N,D) tensor = 1048576

typedef _Float16 f16;
typedef _Float16 f16x8 __attribute__((ext_vector_type(8)));
typedef _Float16 f16x4 __attribute__((ext_vector_type(4)));
typedef float f32x4 __attribute__((ext_vector_type(4)));

// Swizzled element index within a [rows][64] f16 LDS tile (128B rows).
// XOR row-bits into the 16B-granule bits so ds_read_b128 of a 16-row column
// slab spreads over all 8 bank-granules (2-way residual = free, m136).
__device__ __forceinline__ int swz(int row, int col) {
    return row * 64 + (col ^ ((row & 7) << 3));
}

// ---------------------------------------------------------------------------
// Kernel 1: fused 1x1 convs. Writes Qh/Ql (fp16 hi/lo split), Kh/Kl, Vh.
// grid (64 pos-blocks, 4 batches) x 256 threads.
// Thread (og = t>>6, pl = t&63): position p = 64*blk + pl, outputs o = og*16..+15.
__global__ __launch_bounds__(256) void qkv_conv(
    const float* __restrict__ v1, const float* __restrict__ v2,
    const float* __restrict__ wq, const float* __restrict__ bq,
    const float* __restrict__ wk, const float* __restrict__ bk,
    const float* __restrict__ wv, const float* __restrict__ bv,
    f16* __restrict__ Qh, f16* __restrict__ Ql,
    f16* __restrict__ Kh, f16* __restrict__ Kl,
    f16* __restrict__ Vh)
{
    __shared__ float wl[2][64][64];
    __shared__ float bl[2][64];
    const int t  = threadIdx.x;
    const int pl = t & 63, og = t >> 6;   // og uniform per wave -> LDS broadcast
    const int b  = blockIdx.y;
    const int p  = blockIdx.x * 64 + pl;
    const float* x1 = v1 + (size_t)b * Cc * HW + p;
    const float* x2 = v2 + (size_t)b * Cc * HW + p;

    // ---- Q phase ----
    for (int i = t; i < 4096; i += 256) wl[0][i >> 6][i & 63] = wq[i];
    if (t < 64) bl[0][t] = bq[t];
    __syncthreads();
    {
        float acc[16];
        #pragma unroll
        for (int j = 0; j < 16; ++j) acc[j] = bl[0][og * 16 + j];
        for (int c = 0; c < 64; ++c) {
            float xc = x1[c * HW];
            #pragma unroll
            for (int j = 0; j < 16; ++j) acc[j] += wl[0][og * 16 + j][c] * xc;
        }
        #pragma unroll
        for (int j = 0; j < 16; ++j) {
            int o = og * 16 + j;
            size_t idx = (size_t)b * (Nn * Dd) + (size_t)o * 4096 + p;
            f16 hi = (f16)acc[j];
            Qh[idx] = hi;
            Ql[idx] = (f16)(acc[j] - (float)hi);
        }
    }
    __syncthreads();
    // ---- K + V phase (one pass over v2) ----
    for (int i = t; i < 4096; i += 256) {
        wl[0][i >> 6][i & 63] = wk[i];
        wl[1][i >> 6][i & 63] = wv[i];
    }
    if (t < 64) { bl[0][t] = bk[t]; bl[1][t] = bv[t]; }
    __syncthreads();
    {
        float ak[16], av[16];
        #pragma unroll
        for (int j = 0; j < 16; ++j) { ak[j] = bl[0][og * 16 + j]; av[j] = bl[1][og * 16 + j]; }
        for (int c = 0; c < 64; ++c) {
            float xc = x2[c * HW];
            #pragma unroll
            for (int j = 0; j < 16; ++j) {
                ak[j] += wl[0][og * 16 + j][c] * xc;
                av[j] += wl[1][og * 16 + j][c] * xc;
            }
        }
        #pragma unroll
        for (int j = 0; j < 16; ++j) {
            int o = og * 16 + j;
            size_t idx = (size_t)b * (Nn * Dd) + (size_t)o * 4096 + p;
            f16 hi = (f16)ak[j];
            Kh[idx] = hi;
            Kl[idx] = (f16)(ak[j] - (float)hi);
            Vh[idx] = (f16)av[j];
        }
    }
}

// ---------------------------------------------------------------------------
// Kernel 2: transpose V (B,N,D) -> Vt (B,D,N) so attention can load B-fragments
// as contiguous rows. grid (64 n-tiles, 4 batches) x 256 threads.
__global__ __launch_bounds__(256) void vtrans(const f16* __restrict__ Vh,
                                              f16* __restrict__ Vt)
{
    __shared__ f16 tile[64][72];  // +8 pad breaks bank alignment
    const int t  = threadIdx.x;
    const int n0 = blockIdx.x * 64;
    const int b  = blockIdx.y;
    for (int i = t; i < 4096; i += 256) {
        int r = i >> 6, c = i & 63;
        tile[r][c] = Vh[(size_t)b * (Nn * Dd) + (size_t)(n0 + r) * 64 + c];
    }
    __syncthreads();
    for (int i = t; i < 4096; i += 256) {
        int w = i >> 6, n = i & 63;
        Vt[(size_t)b * (Dd * Nn) + (size_t)w * Nn + n0 + n] = tile[n][w];
    }
}

// ---------------------------------------------------------------------------
// Kernel 3: flash attention. grid (64 q-blocks, 4 batches) x 256 threads (4 waves).
// Wave wv owns q-rows [n0 + 16*wv, +16). K-tiles of 64 keys.
// S^T = mfma(A=K, B=Q^T): lane holds S[key = fm*16 + g*4 + r][qrow = c]
// where g = lane>>4, c = lane&15 -> row softmax reduces via shfl_xor 16,32.
__global__ __launch_bounds__(256) void attn(
    const f16* __restrict__ Qhg, const f16* __restrict__ Qlg,
    const f16* __restrict__ Khg, const f16* __restrict__ Klg,
    const f16* __restrict__ Vtg, float* __restrict__ out)
{
    __shared__ __align__(16) f16 KhT[4096];
    __shared__ __align__(16) f16 KlT[4096];
    __shared__ __align__(16) f16 VtT[4096];
    __shared__ __align__(16) f16 Pt[4096];

    const int t    = threadIdx.x;
    const int lane = t & 63, wvi = t >> 6;
    const int g = lane >> 4, c = lane & 15;
    const int b  = blockIdx.y;
    const int n0 = blockIdx.x * 64;

    // Hoist Q B-fragments (hi and lo) into registers: B[k=w][col=qrow].
    // Lane reads its q-row's 8 contiguous w at w0 = ks*32 + g*8.
    const int qrow = n0 + wvi * 16 + c;
    const f16* qhp = Qhg + ((size_t)b * Nn + qrow) * 64;
    const f16* qlp = Qlg + ((size_t)b * Nn + qrow) * 64;
    f16x8 qbh[2], qbl[2];
    #pragma unroll
    for (int ks = 0; ks < 2; ++ks) {
        qbh[ks] = *(const f16x8*)(qhp + ks * 32 + g * 8);
        qbl[ks] = *(const f16x8*)(qlp + ks * 32 + g * 8);
    }

    float m_run = -1e30f, l_run = 0.f;
    f32x4 of[4];
    #pragma unroll
    for (int nf = 0; nf < 4; ++nf)
        #pragma unroll
        for (int r = 0; r < 4; ++r) of[nf][r] = 0.f;

    for (int kt = 0; kt < 64; ++kt) {
        const int k0 = kt * 64;
        __syncthreads();   // previous tile's LDS reads complete
        // Stage Kh, Kl, Vt tiles (8KB each) with swizzled ds_write_b128.
        #pragma unroll
        for (int ch = 0; ch < 2; ++ch) {
            int lin = t + ch * 256;
            int row = lin >> 3, col8 = (lin & 7) * 8;
            f16x8 a = *(const f16x8*)(Khg + ((size_t)b * Nn + k0 + row) * 64 + col8);
            *(f16x8*)(KhT + swz(row, col8)) = a;
            f16x8 bb = *(const f16x8*)(Klg + ((size_t)b * Nn + k0 + row) * 64 + col8);
            *(f16x8*)(KlT + swz(row, col8)) = bb;
            f16x8 vv = *(const f16x8*)(Vtg + ((size_t)b * Dd + row) * (size_t)Nn + k0 + col8);
            *(f16x8*)(VtT + swz(row, col8)) = vv;
        }
        __syncthreads();

        // S^T = K·Q^T, 3-pass fp16 hi/lo: Kh·Qh + Kh·Ql + Kl·Qh (near-fp32 exact)
        f32x4 accS[4];
        #pragma unroll
        for (int fm = 0; fm < 4; ++fm)
            #pragma unroll
            for (int r = 0; r < 4; ++r) accS[fm][r] = 0.f;
        #pragma unroll
        for (int fm = 0; fm < 4; ++fm) {
            const int key = fm * 16 + c;
            #pragma unroll
            for (int ks = 0; ks < 2; ++ks) {
                f16x8 kh = *(const f16x8*)(KhT + swz(key, ks * 32 + g * 8));
                f16x8 kl = *(const f16x8*)(KlT + swz(key, ks * 32 + g * 8));
                accS[fm] = __builtin_amdgcn_mfma_f32_16x16x32_f16(kl, qbh[ks], accS[fm], 0, 0, 0);
                accS[fm] = __builtin_amdgcn_mfma_f32_16x16x32_f16(kh, qbl[ks], accS[fm], 0, 0, 0);
                accS[fm] = __builtin_amdgcn_mfma_f32_16x16x32_f16(kh, qbh[ks], accS[fm], 0, 0, 0);
            }
        }

        // Online softmax (fp32). Lane's 16 scores all belong to q-row `c`.
        float tmax = -1e30f;
        #pragma unroll
        for (int fm = 0; fm < 4; ++fm)
            #pragma unroll
            for (int r = 0; r < 4; ++r) tmax = fmaxf(tmax, accS[fm][r]);
        tmax = fmaxf(tmax, __shfl_xor(tmax, 16));
        tmax = fmaxf(tmax, __shfl_xor(tmax, 32));
        const float mnew = fmaxf(m_run, tmax);
        const float corr = __expf(m_run - mnew);
        float pv_[4][4];
        float tsum = 0.f;
        #pragma unroll
        for (int fm = 0; fm < 4; ++fm)
            #pragma unroll
            for (int r = 0; r < 4; ++r) {
                float pp = __expf(accS[fm][r] - mnew);
                pv_[fm][r] = pp;
                tsum += pp;
            }
        tsum += __shfl_xor(tsum, 16);
        tsum += __shfl_xor(tsum, 32);
        l_run = l_run * corr + tsum;
        m_run = mnew;

        // Rescale O: O-frag rows are qrow_local = g*4 + r; corr lives keyed by c.
        #pragma unroll
        for (int r = 0; r < 4; ++r) {
            float cr = __shfl(corr, g * 4 + r);
            #pragma unroll
            for (int nf = 0; nf < 4; ++nf) of[nf][r] *= cr;
        }

        // P -> LDS fp16 (per-wave private rows; same-wave write->read, no barrier)
        const int prow = wvi * 16 + c;
        #pragma unroll
        for (int fm = 0; fm < 4; ++fm) {
            f16x4 pk;
            #pragma unroll
            for (int r = 0; r < 4; ++r) pk[r] = (f16)pv_[fm][r];
            *(f16x4*)(Pt + swz(prow, fm * 16 + g * 4)) = pk;
        }

        // PV: O(16xD) += P(16x64) · V(64xD)
        #pragma unroll
        for (int ks = 0; ks < 2; ++ks) {
            f16x8 pa = *(const f16x8*)(Pt + swz(prow, ks * 32 + g * 8));
            #pragma unroll
            for (int nf = 0; nf < 4; ++nf) {
                f16x8 vb = *(const f16x8*)(VtT + swz(nf * 16 + c, ks * 32 + g * 8));
                of[nf] = __builtin_amdgcn_mfma_f32_16x16x32_f16(pa, vb, of[nf], 0, 0, 0);
            }
        }
    }

    // Epilogue: divide by l, write fp32 out (coalesced 64B segments).
    const float linv = 1.0f / l_run;
    #pragma unroll
    for (int r = 0; r < 4; ++r) {
        float li = __shfl(linv, g * 4 + r);
        int n = n0 + wvi * 16 + g * 4 + r;
        #pragma unroll
        for (int nf = 0; nf < 4; ++nf) {
            out[((size_t)b * Nn + n) * 64 + nf * 16 + c] = of[nf][r] * li;
        }
    }
}

// ---------------------------------------------------------------------------
extern "C" void kernel_launch(void* const* d_in, const int* in_sizes, int n_in,
                              void* d_out, int out_size, void* d_ws, size_t ws_size,
                              hipStream_t stream)
{
    const float* v1 = (const float*)d_in[0];
    const float* v2 = (const float*)d_in[1];
    const float* wq = (const float*)d_in[2];
    const float* bq = (const float*)d_in[3];
    const float* wk = (const float*)d_in[4];
    const float* bk = (const float*)d_in[5];
    const float* wv = (const float*)d_in[6];
    const float* bv = (const float*)d_in[7];
    float* out = (float*)d_out;

    char* ws = (char*)d_ws;
    const size_t T = (size_t)TS * sizeof(f16);  // 2 MB per tensor; needs 12 MB ws
    f16* Qh = (f16*)(ws + 0 * T);
    f16* Ql = (f16*)(ws + 1 * T);
    f16* Kh = (f16*)(ws + 2 * T);
    f16* Kl = (f16*)(ws + 3 * T);
    f16* Vh = (f16*)(ws + 4 * T);
    f16* Vt = (f16*)(ws + 5 * T);

    qkv_conv<<<dim3(64, 4), 256, 0, stream>>>(v1, v2, wq, bq, wk, bk, wv, bv,
                                              Qh, Ql, Kh, Kl, Vh);
    vtrans<<<dim3(64, 4), 256, 0, stream>>>(Vh, Vt);
    attn<<<dim3(64, 4), 256, 0, stream>>>(Qh, Ql, Kh, Kl, Vt, out);
}

// Round 2
// 124.203 us; speedup vs baseline: 1.8857x; 1.8857x over previous
//
#include <hip/hip_runtime.h>

// Problem: B=4, C=64, H=64, W=64. Tokens N = C*H = 4096, feature dim D = W = 64.
// q = conv1x1(v1,wq,bq); k,v = conv1x1(v2,...); scores = q@k^T (no scale);
// softmax; out = attn@v. Output fp32, same flat layout as input (B,C,H,W).
//
// R2: flash SPLIT-K attention. R1 showed Occupancy 11% (1 wave/SIMD) with both
// MFMA (7.6%) and VALU (12.5%) idle -> latency-bound. Splitting the 4096-key
// loop into S=4 slices gives 1024 blocks (16 waves/CU) + a cheap combine pass.

#define Bn 4
#define Cc 64
#define HW 4096
#define Nn 4096
#define Dd 64
#define TS (Bn * Nn * Dd)   // elems per (B,N,D) tensor = 1048576

typedef _Float16 f16;
typedef _Float16 f16x8 __attribute__((ext_vector_type(8)));
typedef _Float16 f16x4 __attribute__((ext_vector_type(4)));
typedef float f32x4 __attribute__((ext_vector_type(4)));

// Swizzled element index within a [rows][64] f16 LDS tile (128B rows).
__device__ __forceinline__ int swz(int row, int col) {
    return row * 64 + (col ^ ((row & 7) << 3));
}

// ---------------------------------------------------------------------------
// Kernel 1: fused 1x1 convs. Writes Qh/Ql (fp16 hi/lo split), Kh/Kl, Vh.
__global__ __launch_bounds__(256) void qkv_conv(
    const float* __restrict__ v1, const float* __restrict__ v2,
    const float* __restrict__ wq, const float* __restrict__ bq,
    const float* __restrict__ wk, const float* __restrict__ bk,
    const float* __restrict__ wv, const float* __restrict__ bv,
    f16* __restrict__ Qh, f16* __restrict__ Ql,
    f16* __restrict__ Kh, f16* __restrict__ Kl,
    f16* __restrict__ Vh)
{
    __shared__ float wl[2][64][64];
    __shared__ float bl[2][64];
    const int t  = threadIdx.x;
    const int pl = t & 63, og = t >> 6;
    const int b  = blockIdx.y;
    const int p  = blockIdx.x * 64 + pl;
    const float* x1 = v1 + (size_t)b * Cc * HW + p;
    const float* x2 = v2 + (size_t)b * Cc * HW + p;

    for (int i = t; i < 4096; i += 256) wl[0][i >> 6][i & 63] = wq[i];
    if (t < 64) bl[0][t] = bq[t];
    __syncthreads();
    {
        float acc[16];
        #pragma unroll
        for (int j = 0; j < 16; ++j) acc[j] = bl[0][og * 16 + j];
        for (int c = 0; c < 64; ++c) {
            float xc = x1[c * HW];
            #pragma unroll
            for (int j = 0; j < 16; ++j) acc[j] += wl[0][og * 16 + j][c] * xc;
        }
        #pragma unroll
        for (int j = 0; j < 16; ++j) {
            int o = og * 16 + j;
            size_t idx = (size_t)b * (Nn * Dd) + (size_t)o * 4096 + p;
            f16 hi = (f16)acc[j];
            Qh[idx] = hi;
            Ql[idx] = (f16)(acc[j] - (float)hi);
        }
    }
    __syncthreads();
    for (int i = t; i < 4096; i += 256) {
        wl[0][i >> 6][i & 63] = wk[i];
        wl[1][i >> 6][i & 63] = wv[i];
    }
    if (t < 64) { bl[0][t] = bk[t]; bl[1][t] = bv[t]; }
    __syncthreads();
    {
        float ak[16], av[16];
        #pragma unroll
        for (int j = 0; j < 16; ++j) { ak[j] = bl[0][og * 16 + j]; av[j] = bl[1][og * 16 + j]; }
        for (int c = 0; c < 64; ++c) {
            float xc = x2[c * HW];
            #pragma unroll
            for (int j = 0; j < 16; ++j) {
                ak[j] += wl[0][og * 16 + j][c] * xc;
                av[j] += wl[1][og * 16 + j][c] * xc;
            }
        }
        #pragma unroll
        for (int j = 0; j < 16; ++j) {
            int o = og * 16 + j;
            size_t idx = (size_t)b * (Nn * Dd) + (size_t)o * 4096 + p;
            f16 hi = (f16)ak[j];
            Kh[idx] = hi;
            Kl[idx] = (f16)(ak[j] - (float)hi);
            Vh[idx] = (f16)av[j];
        }
    }
}

// ---------------------------------------------------------------------------
// Kernel 2: transpose V (B,N,D) -> Vt (B,D,N).
__global__ __launch_bounds__(256) void vtrans(const f16* __restrict__ Vh,
                                              f16* __restrict__ Vt)
{
    __shared__ f16 tile[64][72];
    const int t  = threadIdx.x;
    const int n0 = blockIdx.x * 64;
    const int b  = blockIdx.y;
    for (int i = t; i < 4096; i += 256) {
        int r = i >> 6, c = i & 63;
        tile[r][c] = Vh[(size_t)b * (Nn * Dd) + (size_t)(n0 + r) * 64 + c];
    }
    __syncthreads();
    for (int i = t; i < 4096; i += 256) {
        int w = i >> 6, n = i & 63;
        Vt[(size_t)b * (Dd * Nn) + (size_t)w * Nn + n0 + n] = tile[n][w];
    }
}

// ---------------------------------------------------------------------------
// Kernel 3: flash attention, split-K. grid (64 q-blocks, S splits, 4 batches)
// x 256 threads (4 waves, 16 q-rows each). Each block handles keys
// [split*(N/S), +(N/S)). If S==1 writes normalized out directly; else writes
// unnormalized O-partial + (m,l) per row for the combine kernel.
__global__ __launch_bounds__(256) void attn(
    const f16* __restrict__ Qhg, const f16* __restrict__ Qlg,
    const f16* __restrict__ Khg, const f16* __restrict__ Klg,
    const f16* __restrict__ Vtg, float* __restrict__ out,
    float* __restrict__ Opart, float2* __restrict__ ml)
{
    __shared__ __align__(16) f16 KhT[4096];
    __shared__ __align__(16) f16 KlT[4096];
    __shared__ __align__(16) f16 VtT[4096];
    __shared__ __align__(16) f16 Pt[4096];

    const int t    = threadIdx.x;
    const int lane = t & 63, wvi = t >> 6;
    const int g = lane >> 4, c = lane & 15;
    const int b  = blockIdx.z;
    const int sp = blockIdx.y;
    const int S  = gridDim.y;
    const int n0 = blockIdx.x * 64;
    const int keysPerSplit = Nn / S;
    const int nTiles = keysPerSplit / 64;
    const int kbase = sp * keysPerSplit;

    const int qrow = n0 + wvi * 16 + c;
    const f16* qhp = Qhg + ((size_t)b * Nn + qrow) * 64;
    const f16* qlp = Qlg + ((size_t)b * Nn + qrow) * 64;
    f16x8 qbh[2], qbl[2];
    #pragma unroll
    for (int ks = 0; ks < 2; ++ks) {
        qbh[ks] = *(const f16x8*)(qhp + ks * 32 + g * 8);
        qbl[ks] = *(const f16x8*)(qlp + ks * 32 + g * 8);
    }

    float m_run = -1e30f, l_run = 0.f;
    f32x4 of[4];
    #pragma unroll
    for (int nf = 0; nf < 4; ++nf)
        #pragma unroll
        for (int r = 0; r < 4; ++r) of[nf][r] = 0.f;

    for (int kt = 0; kt < nTiles; ++kt) {
        const int k0 = kbase + kt * 64;
        __syncthreads();
        #pragma unroll
        for (int ch = 0; ch < 2; ++ch) {
            int lin = t + ch * 256;
            int row = lin >> 3, col8 = (lin & 7) * 8;
            f16x8 a = *(const f16x8*)(Khg + ((size_t)b * Nn + k0 + row) * 64 + col8);
            *(f16x8*)(KhT + swz(row, col8)) = a;
            f16x8 bb = *(const f16x8*)(Klg + ((size_t)b * Nn + k0 + row) * 64 + col8);
            *(f16x8*)(KlT + swz(row, col8)) = bb;
            f16x8 vv = *(const f16x8*)(Vtg + ((size_t)b * Dd + row) * (size_t)Nn + k0 + col8);
            *(f16x8*)(VtT + swz(row, col8)) = vv;
        }
        __syncthreads();

        // S^T = K·Q^T, 3-pass fp16 hi/lo (near-fp32 exact)
        f32x4 accS[4];
        #pragma unroll
        for (int fm = 0; fm < 4; ++fm)
            #pragma unroll
            for (int r = 0; r < 4; ++r) accS[fm][r] = 0.f;
        #pragma unroll
        for (int fm = 0; fm < 4; ++fm) {
            const int key = fm * 16 + c;
            #pragma unroll
            for (int ks = 0; ks < 2; ++ks) {
                f16x8 kh = *(const f16x8*)(KhT + swz(key, ks * 32 + g * 8));
                f16x8 kl = *(const f16x8*)(KlT + swz(key, ks * 32 + g * 8));
                accS[fm] = __builtin_amdgcn_mfma_f32_16x16x32_f16(kl, qbh[ks], accS[fm], 0, 0, 0);
                accS[fm] = __builtin_amdgcn_mfma_f32_16x16x32_f16(kh, qbl[ks], accS[fm], 0, 0, 0);
                accS[fm] = __builtin_amdgcn_mfma_f32_16x16x32_f16(kh, qbh[ks], accS[fm], 0, 0, 0);
            }
        }

        // Online softmax (fp32); lane's 16 scores belong to q-row `c`.
        float tmax = -1e30f;
        #pragma unroll
        for (int fm = 0; fm < 4; ++fm)
            #pragma unroll
            for (int r = 0; r < 4; ++r) tmax = fmaxf(tmax, accS[fm][r]);
        tmax = fmaxf(tmax, __shfl_xor(tmax, 16));
        tmax = fmaxf(tmax, __shfl_xor(tmax, 32));
        const float mnew = fmaxf(m_run, tmax);
        const float corr = __expf(m_run - mnew);
        float pv_[4][4];
        float tsum = 0.f;
        #pragma unroll
        for (int fm = 0; fm < 4; ++fm)
            #pragma unroll
            for (int r = 0; r < 4; ++r) {
                float pp = __expf(accS[fm][r] - mnew);
                pv_[fm][r] = pp;
                tsum += pp;
            }
        tsum += __shfl_xor(tsum, 16);
        tsum += __shfl_xor(tsum, 32);
        l_run = l_run * corr + tsum;
        m_run = mnew;

        #pragma unroll
        for (int r = 0; r < 4; ++r) {
            float cr = __shfl(corr, g * 4 + r);
            #pragma unroll
            for (int nf = 0; nf < 4; ++nf) of[nf][r] *= cr;
        }

        const int prow = wvi * 16 + c;
        #pragma unroll
        for (int fm = 0; fm < 4; ++fm) {
            f16x4 pk;
            #pragma unroll
            for (int r = 0; r < 4; ++r) pk[r] = (f16)pv_[fm][r];
            *(f16x4*)(Pt + swz(prow, fm * 16 + g * 4)) = pk;
        }

        #pragma unroll
        for (int ks = 0; ks < 2; ++ks) {
            f16x8 pa = *(const f16x8*)(Pt + swz(prow, ks * 32 + g * 8));
            #pragma unroll
            for (int nf = 0; nf < 4; ++nf) {
                f16x8 vb = *(const f16x8*)(VtT + swz(nf * 16 + c, ks * 32 + g * 8));
                of[nf] = __builtin_amdgcn_mfma_f32_16x16x32_f16(pa, vb, of[nf], 0, 0, 0);
            }
        }
    }

    if (S == 1) {
        const float linv = 1.0f / l_run;
        #pragma unroll
        for (int r = 0; r < 4; ++r) {
            float li = __shfl(linv, g * 4 + r);
            int n = n0 + wvi * 16 + g * 4 + r;
            #pragma unroll
            for (int nf = 0; nf < 4; ++nf)
                out[((size_t)b * Nn + n) * 64 + nf * 16 + c] = of[nf][r] * li;
        }
    } else {
        // Unnormalized partial + (m,l). O-frag rows are g*4+r within the wave.
        #pragma unroll
        for (int r = 0; r < 4; ++r) {
            int n = n0 + wvi * 16 + g * 4 + r;
            size_t robase = (((size_t)sp * Bn + b) * Nn + n) * 64;
            #pragma unroll
            for (int nf = 0; nf < 4; ++nf)
                Opart[robase + nf * 16 + c] = of[nf][r];
        }
        if (lane < 16) {   // one writer per q-row (c == lane)
            int n = n0 + wvi * 16 + c;
            ml[((size_t)sp * Bn + b) * Nn + n] = make_float2(m_run, l_run);
        }
    }
}

// ---------------------------------------------------------------------------
// Kernel 4: combine split partials. 1 thread per output element.
__global__ __launch_bounds__(256) void combine(
    const float* __restrict__ Opart, const float2* __restrict__ ml,
    float* __restrict__ out, int S)
{
    const int idx = blockIdx.x * 256 + threadIdx.x;   // b*(N*64) + n*64 + w
    const int w = idx & 63;
    const int n = (idx >> 6) & (Nn - 1);
    const int b = idx >> 18;
    float M = -1e30f;
    for (int s = 0; s < S; ++s)
        M = fmaxf(M, ml[((size_t)s * Bn + b) * Nn + n].x);
    float num = 0.f, den = 0.f;
    for (int s = 0; s < S; ++s) {
        float2 m2 = ml[((size_t)s * Bn + b) * Nn + n];
        float a = __expf(m2.x - M);
        num += a * Opart[(((size_t)s * Bn + b) * Nn + n) * 64 + w];
        den += a * m2.y;
    }
    out[idx] = num / den;
}

// ---------------------------------------------------------------------------
extern "C" void kernel_launch(void* const* d_in, const int* in_sizes, int n_in,
                              void* d_out, int out_size, void* d_ws, size_t ws_size,
                              hipStream_t stream)
{
    const float* v1 = (const float*)d_in[0];
    const float* v2 = (const float*)d_in[1];
    const float* wq = (const float*)d_in[2];
    const float* bq = (const float*)d_in[3];
    const float* wk = (const float*)d_in[4];
    const float* bk = (const float*)d_in[5];
    const float* wv = (const float*)d_in[6];
    const float* bv = (const float*)d_in[7];
    float* out = (float*)d_out;

    char* ws = (char*)d_ws;
    const size_t T = (size_t)TS * sizeof(f16);  // 2 MB per f16 tensor
    f16* Qh = (f16*)(ws + 0 * T);
    f16* Ql = (f16*)(ws + 1 * T);
    f16* Kh = (f16*)(ws + 2 * T);
    f16* Kl = (f16*)(ws + 3 * T);
    f16* Vh = (f16*)(ws + 4 * T);
    f16* Vt = (f16*)(ws + 5 * T);
    const size_t base = 6 * T;                       // 12 MB
    const size_t opartBytes = (size_t)TS * 4;        // 4 MB per split (fp32)
    const size_t mlBytes    = (size_t)Bn * Nn * 8;   // 128 KB per split

    // Deterministic split-count choice from ws_size.
    int S = 1;
    if (ws_size >= base + 4 * (opartBytes + mlBytes)) S = 4;
    else if (ws_size >= base + 2 * (opartBytes + mlBytes)) S = 2;

    float*  Opart = (float*)(ws + base);
    float2* mlp   = (float2*)(ws + base + (size_t)S * opartBytes);

    qkv_conv<<<dim3(64, 4), 256, 0, stream>>>(v1, v2, wq, bq, wk, bk, wv, bv,
                                              Qh, Ql, Kh, Kl, Vh);
    vtrans<<<dim3(64, 4), 256, 0, stream>>>(Vh, Vt);
    attn<<<dim3(64, S, 4), 256, 0, stream>>>(Qh, Ql, Kh, Kl, Vt, out, Opart, mlp);
    if (S > 1) {
        combine<<<(Bn * Nn * Dd) / 256, 256, 0, stream>>>(Opart, mlp, out, S);
    }
}

// Round 3
// 93.866 us; speedup vs baseline: 2.4952x; 1.3232x over previous
//
#include <hip/hip_runtime.h>

// B=4, C=64, H=64, W=64. Tokens N = C*H = 4096, feature dim D = W = 64.
// q = conv1x1(v1,wq,bq); k,v = conv1x1(v2,...); scores = q@k^T (no scale);
// softmax; out = attn@v. Output fp32, flat (B,C,H,W) == (B,N,D).
//
// R3: (1) conv: 3-way z-split grid + SGPR weights (readfirstlane) -> no LDS,
//     (2) attn: T14 reg-staged prefetch (loads in flight across compute),
//     (3) S=8 split-K when workspace allows; float4 combine.

#define Bn 4
#define Cc 64
#define HW 4096
#define Nn 4096
#define Dd 64
#define TS (Bn * Nn * Dd)   // elems per (B,N,D) tensor = 1048576

typedef _Float16 f16;
typedef _Float16 f16x8 __attribute__((ext_vector_type(8)));
typedef _Float16 f16x4 __attribute__((ext_vector_type(4)));
typedef float f32x4 __attribute__((ext_vector_type(4)));

__device__ __forceinline__ int swz(int row, int col) {
    return row * 64 + (col ^ ((row & 7) << 3));
}

// ---------------------------------------------------------------------------
// Kernel 1: 1x1 conv, one of {Q,K,V} per blockIdx.z. 64 positions/block, wave
// og owns 16 output channels. Weights read via wave-uniform (SGPR) indices.
__global__ __launch_bounds__(256) void qkv_conv(
    const float* __restrict__ v1, const float* __restrict__ v2,
    const float* __restrict__ wq, const float* __restrict__ bq,
    const float* __restrict__ wk, const float* __restrict__ bk,
    const float* __restrict__ wv, const float* __restrict__ bv,
    f16* __restrict__ Qh, f16* __restrict__ Ql,
    f16* __restrict__ Kh, f16* __restrict__ Kl,
    f16* __restrict__ Vh)
{
    const int t    = threadIdx.x;
    const int lane = t & 63;
    const int og   = __builtin_amdgcn_readfirstlane(t >> 6);  // SGPR: uniform
    const int b    = blockIdx.y;
    const int p    = blockIdx.x * 64 + lane;
    const int z    = blockIdx.z;  // 0=Q, 1=K, 2=V

    const float* w    = (z == 0) ? wq : (z == 1) ? wk : wv;
    const float* bias = (z == 0) ? bq : (z == 1) ? bk : bv;
    const float* x    = ((z == 0) ? v1 : v2) + (size_t)b * (Cc * HW) + p;

    float acc[16];
    #pragma unroll
    for (int j = 0; j < 16; ++j) acc[j] = bias[og * 16 + j];
    #pragma unroll 16
    for (int c = 0; c < 64; ++c) {
        float xc = x[c * HW];
        #pragma unroll
        for (int j = 0; j < 16; ++j)
            acc[j] = fmaf(w[(og * 16 + j) * 64 + c], xc, acc[j]);
    }

    if (z == 2) {
        #pragma unroll
        for (int j = 0; j < 16; ++j) {
            size_t idx = (size_t)b * (Nn * Dd) + (size_t)(og * 16 + j) * 4096 + p;
            Vh[idx] = (f16)acc[j];
        }
    } else {
        f16* Hi = (z == 0) ? Qh : Kh;
        f16* Lo = (z == 0) ? Ql : Kl;
        #pragma unroll
        for (int j = 0; j < 16; ++j) {
            size_t idx = (size_t)b * (Nn * Dd) + (size_t)(og * 16 + j) * 4096 + p;
            f16 hi = (f16)acc[j];
            Hi[idx] = hi;
            Lo[idx] = (f16)(acc[j] - (float)hi);
        }
    }
}

// ---------------------------------------------------------------------------
// Kernel 2: transpose V (B,N,D) -> Vt (B,D,N).
__global__ __launch_bounds__(256) void vtrans(const f16* __restrict__ Vh,
                                              f16* __restrict__ Vt)
{
    __shared__ f16 tile[64][72];
    const int t  = threadIdx.x;
    const int n0 = blockIdx.x * 64;
    const int b  = blockIdx.y;
    for (int i = t; i < 4096; i += 256) {
        int r = i >> 6, c = i & 63;
        tile[r][c] = Vh[(size_t)b * (Nn * Dd) + (size_t)(n0 + r) * 64 + c];
    }
    __syncthreads();
    for (int i = t; i < 4096; i += 256) {
        int w = i >> 6, n = i & 63;
        Vt[(size_t)b * (Dd * Nn) + (size_t)w * Nn + n0 + n] = tile[n][w];
    }
}

// ---------------------------------------------------------------------------
// Kernel 3: flash attention, split-K, T14 reg-staged prefetch.
// grid (64 q-blocks, S splits, 4 batches) x 256 threads (4 waves x 16 q-rows).
__global__ __launch_bounds__(256, 4) void attn(
    const f16* __restrict__ Qhg, const f16* __restrict__ Qlg,
    const f16* __restrict__ Khg, const f16* __restrict__ Klg,
    const f16* __restrict__ Vtg, float* __restrict__ out,
    float* __restrict__ Opart, float2* __restrict__ ml)
{
    __shared__ __align__(16) f16 KhT[4096];
    __shared__ __align__(16) f16 KlT[4096];
    __shared__ __align__(16) f16 VtT[4096];
    __shared__ __align__(16) f16 Pt[4096];

    const int t    = threadIdx.x;
    const int lane = t & 63, wvi = t >> 6;
    const int g = lane >> 4, c = lane & 15;
    const int b  = blockIdx.z;
    const int sp = blockIdx.y;
    const int S  = gridDim.y;
    const int n0 = blockIdx.x * 64;
    const int keysPerSplit = Nn / S;
    const int nTiles = keysPerSplit / 64;
    const int kbase = sp * keysPerSplit;

    // Staging geometry: thread covers rows lin>>3 (lin = t + ch*256), col8.
    const int srow0 = t >> 3, scol = (t & 7) * 8;
    const int srow1 = srow0 + 32;

    const int qrow = n0 + wvi * 16 + c;
    const f16* qhp = Qhg + ((size_t)b * Nn + qrow) * 64;
    const f16* qlp = Qlg + ((size_t)b * Nn + qrow) * 64;
    f16x8 qbh[2], qbl[2];
    #pragma unroll
    for (int ks = 0; ks < 2; ++ks) {
        qbh[ks] = *(const f16x8*)(qhp + ks * 32 + g * 8);
        qbl[ks] = *(const f16x8*)(qlp + ks * 32 + g * 8);
    }

    float m_run = -1e30f, l_run = 0.f;
    f32x4 of[4];
    #pragma unroll
    for (int nf = 0; nf < 4; ++nf)
        #pragma unroll
        for (int r = 0; r < 4; ++r) of[nf][r] = 0.f;

    // Prefetch tile 0 into registers.
    f16x8 rKh0, rKh1, rKl0, rKl1, rVt0, rVt1;
    {
        const int k0 = kbase;
        rKh0 = *(const f16x8*)(Khg + ((size_t)b * Nn + k0 + srow0) * 64 + scol);
        rKh1 = *(const f16x8*)(Khg + ((size_t)b * Nn + k0 + srow1) * 64 + scol);
        rKl0 = *(const f16x8*)(Klg + ((size_t)b * Nn + k0 + srow0) * 64 + scol);
        rKl1 = *(const f16x8*)(Klg + ((size_t)b * Nn + k0 + srow1) * 64 + scol);
        rVt0 = *(const f16x8*)(Vtg + ((size_t)b * Dd + srow0) * (size_t)Nn + k0 + scol);
        rVt1 = *(const f16x8*)(Vtg + ((size_t)b * Dd + srow1) * (size_t)Nn + k0 + scol);
    }

    for (int kt = 0; kt < nTiles; ++kt) {
        __syncthreads();   // all waves done reading LDS of previous tile
        *(f16x8*)(KhT + swz(srow0, scol)) = rKh0;
        *(f16x8*)(KhT + swz(srow1, scol)) = rKh1;
        *(f16x8*)(KlT + swz(srow0, scol)) = rKl0;
        *(f16x8*)(KlT + swz(srow1, scol)) = rKl1;
        *(f16x8*)(VtT + swz(srow0, scol)) = rVt0;
        *(f16x8*)(VtT + swz(srow1, scol)) = rVt1;
        __syncthreads();

        // Issue next tile's loads now; they land during compute (T14).
        if (kt + 1 < nTiles) {
            const int k0 = kbase + (kt + 1) * 64;
            rKh0 = *(const f16x8*)(Khg + ((size_t)b * Nn + k0 + srow0) * 64 + scol);
            rKh1 = *(const f16x8*)(Khg + ((size_t)b * Nn + k0 + srow1) * 64 + scol);
            rKl0 = *(const f16x8*)(Klg + ((size_t)b * Nn + k0 + srow0) * 64 + scol);
            rKl1 = *(const f16x8*)(Klg + ((size_t)b * Nn + k0 + srow1) * 64 + scol);
            rVt0 = *(const f16x8*)(Vtg + ((size_t)b * Dd + srow0) * (size_t)Nn + k0 + scol);
            rVt1 = *(const f16x8*)(Vtg + ((size_t)b * Dd + srow1) * (size_t)Nn + k0 + scol);
        }

        // S^T = K·Q^T, 3-pass fp16 hi/lo (near-fp32 exact)
        f32x4 accS[4];
        #pragma unroll
        for (int fm = 0; fm < 4; ++fm)
            #pragma unroll
            for (int r = 0; r < 4; ++r) accS[fm][r] = 0.f;
        #pragma unroll
        for (int fm = 0; fm < 4; ++fm) {
            const int key = fm * 16 + c;
            #pragma unroll
            for (int ks = 0; ks < 2; ++ks) {
                f16x8 kh = *(const f16x8*)(KhT + swz(key, ks * 32 + g * 8));
                f16x8 kl = *(const f16x8*)(KlT + swz(key, ks * 32 + g * 8));
                accS[fm] = __builtin_amdgcn_mfma_f32_16x16x32_f16(kl, qbh[ks], accS[fm], 0, 0, 0);
                accS[fm] = __builtin_amdgcn_mfma_f32_16x16x32_f16(kh, qbl[ks], accS[fm], 0, 0, 0);
                accS[fm] = __builtin_amdgcn_mfma_f32_16x16x32_f16(kh, qbh[ks], accS[fm], 0, 0, 0);
            }
        }

        // Online softmax; lane's 16 scores belong to q-row `c`.
        float tmax = -1e30f;
        #pragma unroll
        for (int fm = 0; fm < 4; ++fm)
            #pragma unroll
            for (int r = 0; r < 4; ++r) tmax = fmaxf(tmax, accS[fm][r]);
        tmax = fmaxf(tmax, __shfl_xor(tmax, 16));
        tmax = fmaxf(tmax, __shfl_xor(tmax, 32));
        const float mnew = fmaxf(m_run, tmax);
        const float corr = __expf(m_run - mnew);
        float tsum = 0.f;
        #pragma unroll
        for (int fm = 0; fm < 4; ++fm)
            #pragma unroll
            for (int r = 0; r < 4; ++r) {
                float pp = __expf(accS[fm][r] - mnew);
                accS[fm][r] = pp;     // in place: saves 16 VGPRs
                tsum += pp;
            }
        tsum += __shfl_xor(tsum, 16);
        tsum += __shfl_xor(tsum, 32);
        l_run = l_run * corr + tsum;
        m_run = mnew;

        #pragma unroll
        for (int r = 0; r < 4; ++r) {
            float cr = __shfl(corr, g * 4 + r);
            #pragma unroll
            for (int nf = 0; nf < 4; ++nf) of[nf][r] *= cr;
        }

        const int prow = wvi * 16 + c;
        #pragma unroll
        for (int fm = 0; fm < 4; ++fm) {
            f16x4 pk;
            #pragma unroll
            for (int r = 0; r < 4; ++r) pk[r] = (f16)accS[fm][r];
            *(f16x4*)(Pt + swz(prow, fm * 16 + g * 4)) = pk;
        }

        #pragma unroll
        for (int ks = 0; ks < 2; ++ks) {
            f16x8 pa = *(const f16x8*)(Pt + swz(prow, ks * 32 + g * 8));
            #pragma unroll
            for (int nf = 0; nf < 4; ++nf) {
                f16x8 vb = *(const f16x8*)(VtT + swz(nf * 16 + c, ks * 32 + g * 8));
                of[nf] = __builtin_amdgcn_mfma_f32_16x16x32_f16(pa, vb, of[nf], 0, 0, 0);
            }
        }
    }

    if (S == 1) {
        const float linv = 1.0f / l_run;
        #pragma unroll
        for (int r = 0; r < 4; ++r) {
            float li = __shfl(linv, g * 4 + r);
            int n = n0 + wvi * 16 + g * 4 + r;
            #pragma unroll
            for (int nf = 0; nf < 4; ++nf)
                out[((size_t)b * Nn + n) * 64 + nf * 16 + c] = of[nf][r] * li;
        }
    } else {
        #pragma unroll
        for (int r = 0; r < 4; ++r) {
            int n = n0 + wvi * 16 + g * 4 + r;
            size_t robase = (((size_t)sp * Bn + b) * Nn + n) * 64;
            #pragma unroll
            for (int nf = 0; nf < 4; ++nf)
                Opart[robase + nf * 16 + c] = of[nf][r];
        }
        if (lane < 16) {
            int n = n0 + wvi * 16 + c;
            ml[((size_t)sp * Bn + b) * Nn + n] = make_float2(m_run, l_run);
        }
    }
}

// ---------------------------------------------------------------------------
// Kernel 4: combine split partials, float4 per thread.
__global__ __launch_bounds__(256) void combine(
    const float4* __restrict__ Opart, const float2* __restrict__ ml,
    float4* __restrict__ out, int S)
{
    const int idx4 = blockIdx.x * 256 + threadIdx.x;  // b*(N*16) + n*16 + w4
    const int w4 = idx4 & 15;
    const int n  = (idx4 >> 4) & (Nn - 1);
    const int b  = idx4 >> 16;
    float M = -1e30f;
    for (int s = 0; s < S; ++s)
        M = fmaxf(M, ml[((size_t)s * Bn + b) * Nn + n].x);
    float4 num = make_float4(0.f, 0.f, 0.f, 0.f);
    float den = 0.f;
    for (int s = 0; s < S; ++s) {
        float2 m2 = ml[((size_t)s * Bn + b) * Nn + n];
        float a = __expf(m2.x - M);
        float4 o4 = Opart[(((size_t)s * Bn + b) * Nn + n) * 16 + w4];
        num.x += a * o4.x; num.y += a * o4.y;
        num.z += a * o4.z; num.w += a * o4.w;
        den += a * m2.y;
    }
    float di = 1.0f / den;
    out[idx4] = make_float4(num.x * di, num.y * di, num.z * di, num.w * di);
}

// ---------------------------------------------------------------------------
extern "C" void kernel_launch(void* const* d_in, const int* in_sizes, int n_in,
                              void* d_out, int out_size, void* d_ws, size_t ws_size,
                              hipStream_t stream)
{
    const float* v1 = (const float*)d_in[0];
    const float* v2 = (const float*)d_in[1];
    const float* wq = (const float*)d_in[2];
    const float* bq = (const float*)d_in[3];
    const float* wk = (const float*)d_in[4];
    const float* bk = (const float*)d_in[5];
    const float* wv = (const float*)d_in[6];
    const float* bv = (const float*)d_in[7];
    float* out = (float*)d_out;

    char* ws = (char*)d_ws;
    const size_t T = (size_t)TS * sizeof(f16);  // 2 MB per f16 tensor
    f16* Qh = (f16*)(ws + 0 * T);
    f16* Ql = (f16*)(ws + 1 * T);
    f16* Kh = (f16*)(ws + 2 * T);
    f16* Kl = (f16*)(ws + 3 * T);
    f16* Vh = (f16*)(ws + 4 * T);
    f16* Vt = (f16*)(ws + 5 * T);
    const size_t base = 6 * T;                       // 12 MB
    const size_t opartBytes = (size_t)TS * 4;        // 4 MB per split (fp32)
    const size_t mlBytes    = (size_t)Bn * Nn * 8;   // 128 KB per split

    int S = 1;
    if (ws_size >= base + 8 * (opartBytes + mlBytes)) S = 8;
    else if (ws_size >= base + 4 * (opartBytes + mlBytes)) S = 4;
    else if (ws_size >= base + 2 * (opartBytes + mlBytes)) S = 2;

    float*  Opart = (float*)(ws + base);
    float2* mlp   = (float2*)(ws + base + (size_t)S * opartBytes);

    qkv_conv<<<dim3(64, 4, 3), 256, 0, stream>>>(v1, v2, wq, bq, wk, bk, wv, bv,
                                                 Qh, Ql, Kh, Kl, Vh);
    vtrans<<<dim3(64, 4), 256, 0, stream>>>(Vh, Vt);
    attn<<<dim3(64, S, 4), 256, 0, stream>>>(Qh, Ql, Kh, Kl, Vt, out, Opart, mlp);
    if (S > 1) {
        combine<<<(Bn * Nn * Dd / 4) / 256, 256, 0, stream>>>(
            (const float4*)Opart, mlp, (float4*)out, S);
    }
}

// Round 4
// 85.952 us; speedup vs baseline: 2.7249x; 1.0921x over previous
//
#include <hip/hip_runtime.h>

// B=4, C=64, H=64, W=64. Tokens N = C*H = 4096, feature dim D = W = 64.
// q = conv1x1(v1,wq,bq); k,v = conv1x1(v2,...); scores = q@k^T (no scale);
// softmax; out = attn@v. Output fp32, flat (B,C,H,W) == (B,N,D).
//
// R4: attn was LDS-pipe bound (26 ds_read_b128/wave-tile for 16 q-rows).
//  (1) 32 q-rows/wave (2 B-frags) -> K/V LDS reads amortized over 2x MFMA,
//  (2) 2-pass QK^T (drop Kl residual; keeps Q hi/lo) -> no Kl tensor at all,
//  (3) block = 128 q-rows, grid (32,S,4); LDS 32KB; launch_bounds(256,3).

#define Bn 4
#define Cc 64
#define HW 4096
#define Nn 4096
#define Dd 64
#define TS (Bn * Nn * Dd)   // elems per (B,N,D) tensor = 1048576

typedef _Float16 f16;
typedef _Float16 f16x8 __attribute__((ext_vector_type(8)));
typedef _Float16 f16x4 __attribute__((ext_vector_type(4)));
typedef float f32x4 __attribute__((ext_vector_type(4)));

__device__ __forceinline__ int swz(int row, int col) {
    return row * 64 + (col ^ ((row & 7) << 3));
}

// ---------------------------------------------------------------------------
// Kernel 1: 1x1 conv, one of {Q,K,V} per blockIdx.z. Wave-uniform (SGPR)
// weight reads; 16 output channels per wave, 64 positions per block.
__global__ __launch_bounds__(256) void qkv_conv(
    const float* __restrict__ v1, const float* __restrict__ v2,
    const float* __restrict__ wq, const float* __restrict__ bq,
    const float* __restrict__ wk, const float* __restrict__ bk,
    const float* __restrict__ wv, const float* __restrict__ bv,
    f16* __restrict__ Qh, f16* __restrict__ Ql,
    f16* __restrict__ Kh, f16* __restrict__ Vh)
{
    const int t    = threadIdx.x;
    const int lane = t & 63;
    const int og   = __builtin_amdgcn_readfirstlane(t >> 6);
    const int b    = blockIdx.y;
    const int p    = blockIdx.x * 64 + lane;
    const int z    = blockIdx.z;  // 0=Q, 1=K, 2=V

    const float* w    = (z == 0) ? wq : (z == 1) ? wk : wv;
    const float* bias = (z == 0) ? bq : (z == 1) ? bk : bv;
    const float* x    = ((z == 0) ? v1 : v2) + (size_t)b * (Cc * HW) + p;

    float acc[16];
    #pragma unroll
    for (int j = 0; j < 16; ++j) acc[j] = bias[og * 16 + j];
    #pragma unroll 16
    for (int c = 0; c < 64; ++c) {
        float xc = x[c * HW];
        #pragma unroll
        for (int j = 0; j < 16; ++j)
            acc[j] = fmaf(w[(og * 16 + j) * 64 + c], xc, acc[j]);
    }

    if (z == 0) {
        #pragma unroll
        for (int j = 0; j < 16; ++j) {
            size_t idx = (size_t)b * (Nn * Dd) + (size_t)(og * 16 + j) * 4096 + p;
            f16 hi = (f16)acc[j];
            Qh[idx] = hi;
            Ql[idx] = (f16)(acc[j] - (float)hi);
        }
    } else {
        f16* dst = (z == 1) ? Kh : Vh;
        #pragma unroll
        for (int j = 0; j < 16; ++j) {
            size_t idx = (size_t)b * (Nn * Dd) + (size_t)(og * 16 + j) * 4096 + p;
            dst[idx] = (f16)acc[j];
        }
    }
}

// ---------------------------------------------------------------------------
// Kernel 2: transpose V (B,N,D) -> Vt (B,D,N).
__global__ __launch_bounds__(256) void vtrans(const f16* __restrict__ Vh,
                                              f16* __restrict__ Vt)
{
    __shared__ f16 tile[64][72];
    const int t  = threadIdx.x;
    const int n0 = blockIdx.x * 64;
    const int b  = blockIdx.y;
    for (int i = t; i < 4096; i += 256) {
        int r = i >> 6, c = i & 63;
        tile[r][c] = Vh[(size_t)b * (Nn * Dd) + (size_t)(n0 + r) * 64 + c];
    }
    __syncthreads();
    for (int i = t; i < 4096; i += 256) {
        int w = i >> 6, n = i & 63;
        Vt[(size_t)b * (Dd * Nn) + (size_t)w * Nn + n0 + n] = tile[n][w];
    }
}

// ---------------------------------------------------------------------------
// Kernel 3: flash attention, split-K, 32 q-rows/wave, 2-pass QK^T.
// grid (32 q-blocks of 128 rows, S splits, 4 batches) x 256 threads (4 waves).
// S^T = mfma(A=Kh, B=Q^T): lane holds S[key=fm*16+g*4+r][qrow = qf-frag row c].
__global__ __launch_bounds__(256, 3) void attn(
    const f16* __restrict__ Qhg, const f16* __restrict__ Qlg,
    const f16* __restrict__ Khg, const f16* __restrict__ Vtg,
    float* __restrict__ out, float* __restrict__ Opart, float2* __restrict__ ml)
{
    __shared__ __align__(16) f16 KhT[4096];   // [key 64][d 64] swizzled
    __shared__ __align__(16) f16 VtT[4096];   // [d 64][key 64] swizzled
    __shared__ __align__(16) f16 Pt[8192];    // [128 qrows][key 64] swizzled

    const int t    = threadIdx.x;
    const int lane = t & 63, wvi = t >> 6;
    const int g = lane >> 4, c = lane & 15;
    const int b  = blockIdx.z;
    const int sp = blockIdx.y;
    const int S  = gridDim.y;
    const int n0 = blockIdx.x * 128;
    const int keysPerSplit = Nn / S;
    const int nTiles = keysPerSplit / 64;
    const int kbase = sp * keysPerSplit;

    const int srow = t >> 3, scol = (t & 7) * 8;   // staging: rows 0..31 (+32)

    // Hoist Q B-fragments for both 16-row sub-frags (qf=0,1).
    f16x8 qbh[2][2], qbl[2][2];
    #pragma unroll
    for (int qf = 0; qf < 2; ++qf) {
        const int qrow = n0 + wvi * 32 + qf * 16 + c;
        const f16* qhp = Qhg + ((size_t)b * Nn + qrow) * 64;
        const f16* qlp = Qlg + ((size_t)b * Nn + qrow) * 64;
        #pragma unroll
        for (int ks = 0; ks < 2; ++ks) {
            qbh[qf][ks] = *(const f16x8*)(qhp + ks * 32 + g * 8);
            qbl[qf][ks] = *(const f16x8*)(qlp + ks * 32 + g * 8);
        }
    }

    float m_run[2] = {-1e30f, -1e30f}, l_run[2] = {0.f, 0.f};
    f32x4 of[2][4];
    #pragma unroll
    for (int qf = 0; qf < 2; ++qf)
        #pragma unroll
        for (int nf = 0; nf < 4; ++nf)
            #pragma unroll
            for (int r = 0; r < 4; ++r) of[qf][nf][r] = 0.f;

    // Prefetch tile 0 (T14): Kh rows (keys), Vt rows (d).
    f16x8 rK0, rK1, rV0, rV1;
    {
        const int k0 = kbase;
        rK0 = *(const f16x8*)(Khg + ((size_t)b * Nn + k0 + srow) * 64 + scol);
        rK1 = *(const f16x8*)(Khg + ((size_t)b * Nn + k0 + srow + 32) * 64 + scol);
        rV0 = *(const f16x8*)(Vtg + ((size_t)b * Dd + srow) * (size_t)Nn + k0 + scol);
        rV1 = *(const f16x8*)(Vtg + ((size_t)b * Dd + srow + 32) * (size_t)Nn + k0 + scol);
    }

    for (int kt = 0; kt < nTiles; ++kt) {
        __syncthreads();   // all waves done reading previous tile's LDS
        *(f16x8*)(KhT + swz(srow, scol))      = rK0;
        *(f16x8*)(KhT + swz(srow + 32, scol)) = rK1;
        *(f16x8*)(VtT + swz(srow, scol))      = rV0;
        *(f16x8*)(VtT + swz(srow + 32, scol)) = rV1;
        __syncthreads();

        // Issue next tile's global loads; land under compute (T14).
        if (kt + 1 < nTiles) {
            const int k0 = kbase + (kt + 1) * 64;
            rK0 = *(const f16x8*)(Khg + ((size_t)b * Nn + k0 + srow) * 64 + scol);
            rK1 = *(const f16x8*)(Khg + ((size_t)b * Nn + k0 + srow + 32) * 64 + scol);
            rV0 = *(const f16x8*)(Vtg + ((size_t)b * Dd + srow) * (size_t)Nn + k0 + scol);
            rV1 = *(const f16x8*)(Vtg + ((size_t)b * Dd + srow + 32) * (size_t)Nn + k0 + scol);
        }

        // ---- QK^T, 2-pass (Kh*Qh + Kh*Ql): one K-read feeds 4 MFMAs ----
        f32x4 accS[2][4];
        #pragma unroll
        for (int qf = 0; qf < 2; ++qf)
            #pragma unroll
            for (int fm = 0; fm < 4; ++fm)
                #pragma unroll
                for (int r = 0; r < 4; ++r) accS[qf][fm][r] = 0.f;
        #pragma unroll
        for (int fm = 0; fm < 4; ++fm) {
            const int key = fm * 16 + c;
            #pragma unroll
            for (int ks = 0; ks < 2; ++ks) {
                f16x8 kh = *(const f16x8*)(KhT + swz(key, ks * 32 + g * 8));
                #pragma unroll
                for (int qf = 0; qf < 2; ++qf) {
                    accS[qf][fm] = __builtin_amdgcn_mfma_f32_16x16x32_f16(kh, qbl[qf][ks], accS[qf][fm], 0, 0, 0);
                    accS[qf][fm] = __builtin_amdgcn_mfma_f32_16x16x32_f16(kh, qbh[qf][ks], accS[qf][fm], 0, 0, 0);
                }
            }
        }

        // ---- online softmax per q-frag (lane's scores belong to q-row c) ----
        float corr[2];
        #pragma unroll
        for (int qf = 0; qf < 2; ++qf) {
            float tmax = -1e30f;
            #pragma unroll
            for (int fm = 0; fm < 4; ++fm)
                #pragma unroll
                for (int r = 0; r < 4; ++r) tmax = fmaxf(tmax, accS[qf][fm][r]);
            tmax = fmaxf(tmax, __shfl_xor(tmax, 16));
            tmax = fmaxf(tmax, __shfl_xor(tmax, 32));
            const float mnew = fmaxf(m_run[qf], tmax);
            corr[qf] = __expf(m_run[qf] - mnew);
            float tsum = 0.f;
            #pragma unroll
            for (int fm = 0; fm < 4; ++fm)
                #pragma unroll
                for (int r = 0; r < 4; ++r) {
                    float pp = __expf(accS[qf][fm][r] - mnew);
                    accS[qf][fm][r] = pp;
                    tsum += pp;
                }
            tsum += __shfl_xor(tsum, 16);
            tsum += __shfl_xor(tsum, 32);
            l_run[qf] = l_run[qf] * corr[qf] + tsum;
            m_run[qf] = mnew;
        }

        // ---- rescale O, stash P to LDS (wave-private rows) ----
        #pragma unroll
        for (int qf = 0; qf < 2; ++qf) {
            #pragma unroll
            for (int r = 0; r < 4; ++r) {
                float cr = __shfl(corr[qf], g * 4 + r);
                #pragma unroll
                for (int nf = 0; nf < 4; ++nf) of[qf][nf][r] *= cr;
            }
            const int prow = wvi * 32 + qf * 16 + c;
            #pragma unroll
            for (int fm = 0; fm < 4; ++fm) {
                f16x4 pk;
                #pragma unroll
                for (int r = 0; r < 4; ++r) pk[r] = (f16)accS[qf][fm][r];
                *(f16x4*)(Pt + swz(prow, fm * 16 + g * 4)) = pk;
            }
        }

        // ---- PV: one V-read feeds both q-frags ----
        #pragma unroll
        for (int ks = 0; ks < 2; ++ks) {
            f16x8 pa0 = *(const f16x8*)(Pt + swz(wvi * 32 + c,      ks * 32 + g * 8));
            f16x8 pa1 = *(const f16x8*)(Pt + swz(wvi * 32 + 16 + c, ks * 32 + g * 8));
            #pragma unroll
            for (int nf = 0; nf < 4; ++nf) {
                f16x8 vb = *(const f16x8*)(VtT + swz(nf * 16 + c, ks * 32 + g * 8));
                of[0][nf] = __builtin_amdgcn_mfma_f32_16x16x32_f16(pa0, vb, of[0][nf], 0, 0, 0);
                of[1][nf] = __builtin_amdgcn_mfma_f32_16x16x32_f16(pa1, vb, of[1][nf], 0, 0, 0);
            }
        }
    }

    if (S == 1) {
        #pragma unroll
        for (int qf = 0; qf < 2; ++qf) {
            const float linv = 1.0f / l_run[qf];
            #pragma unroll
            for (int r = 0; r < 4; ++r) {
                float li = __shfl(linv, g * 4 + r);
                int n = n0 + wvi * 32 + qf * 16 + g * 4 + r;
                #pragma unroll
                for (int nf = 0; nf < 4; ++nf)
                    out[((size_t)b * Nn + n) * 64 + nf * 16 + c] = of[qf][nf][r] * li;
            }
        }
    } else {
        #pragma unroll
        for (int qf = 0; qf < 2; ++qf) {
            #pragma unroll
            for (int r = 0; r < 4; ++r) {
                int n = n0 + wvi * 32 + qf * 16 + g * 4 + r;
                size_t robase = (((size_t)sp * Bn + b) * Nn + n) * 64;
                #pragma unroll
                for (int nf = 0; nf < 4; ++nf)
                    Opart[robase + nf * 16 + c] = of[qf][nf][r];
            }
            if (lane < 16) {
                int n = n0 + wvi * 32 + qf * 16 + c;
                ml[((size_t)sp * Bn + b) * Nn + n] = make_float2(m_run[qf], l_run[qf]);
            }
        }
    }
}

// ---------------------------------------------------------------------------
// Kernel 4: combine split partials, float4 per thread.
__global__ __launch_bounds__(256) void combine(
    const float4* __restrict__ Opart, const float2* __restrict__ ml,
    float4* __restrict__ out, int S)
{
    const int idx4 = blockIdx.x * 256 + threadIdx.x;  // b*(N*16) + n*16 + w4
    const int w4 = idx4 & 15;
    const int n  = (idx4 >> 4) & (Nn - 1);
    const int b  = idx4 >> 16;
    float M = -1e30f;
    for (int s = 0; s < S; ++s)
        M = fmaxf(M, ml[((size_t)s * Bn + b) * Nn + n].x);
    float4 num = make_float4(0.f, 0.f, 0.f, 0.f);
    float den = 0.f;
    for (int s = 0; s < S; ++s) {
        float2 m2 = ml[((size_t)s * Bn + b) * Nn + n];
        float a = __expf(m2.x - M);
        float4 o4 = Opart[(((size_t)s * Bn + b) * Nn + n) * 16 + w4];
        num.x += a * o4.x; num.y += a * o4.y;
        num.z += a * o4.z; num.w += a * o4.w;
        den += a * m2.y;
    }
    float di = 1.0f / den;
    out[idx4] = make_float4(num.x * di, num.y * di, num.z * di, num.w * di);
}

// ---------------------------------------------------------------------------
extern "C" void kernel_launch(void* const* d_in, const int* in_sizes, int n_in,
                              void* d_out, int out_size, void* d_ws, size_t ws_size,
                              hipStream_t stream)
{
    const float* v1 = (const float*)d_in[0];
    const float* v2 = (const float*)d_in[1];
    const float* wq = (const float*)d_in[2];
    const float* bq = (const float*)d_in[3];
    const float* wk = (const float*)d_in[4];
    const float* bk = (const float*)d_in[5];
    const float* wv = (const float*)d_in[6];
    const float* bv = (const float*)d_in[7];
    float* out = (float*)d_out;

    char* ws = (char*)d_ws;
    const size_t T = (size_t)TS * sizeof(f16);  // 2 MB per f16 tensor
    f16* Qh = (f16*)(ws + 0 * T);
    f16* Ql = (f16*)(ws + 1 * T);
    f16* Kh = (f16*)(ws + 2 * T);
    f16* Vh = (f16*)(ws + 3 * T);
    f16* Vt = (f16*)(ws + 4 * T);
    const size_t base = 5 * T;                       // 10 MB
    const size_t opartBytes = (size_t)TS * 4;        // 4 MB per split (fp32)
    const size_t mlBytes    = (size_t)Bn * Nn * 8;   // 128 KB per split

    int S = 1;
    if (ws_size >= base + 8 * (opartBytes + mlBytes)) S = 8;
    else if (ws_size >= base + 4 * (opartBytes + mlBytes)) S = 4;
    else if (ws_size >= base + 2 * (opartBytes + mlBytes)) S = 2;

    float*  Opart = (float*)(ws + base);
    float2* mlp   = (float2*)(ws + base + (size_t)S * opartBytes);

    qkv_conv<<<dim3(64, 4, 3), 256, 0, stream>>>(v1, v2, wq, bq, wk, bk, wv, bv,
                                                 Qh, Ql, Kh, Vh);
    vtrans<<<dim3(64, 4), 256, 0, stream>>>(Vh, Vt);
    attn<<<dim3(32, S, 4), 256, 0, stream>>>(Qh, Ql, Kh, Vt, out, Opart, mlp);
    if (S > 1) {
        combine<<<(Bn * Nn * Dd / 4) / 256, 256, 0, stream>>>(
            (const float4*)Opart, mlp, (float4*)out, S);
    }
}